// Round 4
// baseline (245.122 us; speedup 1.0000x reference)
//
#include <hip/hip_runtime.h>
#include <hip/hip_bf16.h>
#include <stdint.h>
#include <stddef.h>

// Problem constants (from reference). Harness dtype: fp32 in / fp32 out
// (verified round 2: WRITE_SIZE ~90 MB = 2048*10788*4B).
#define NUM_FEATURES 256
#define NUM_PIDS 5532
#define CQ_SIZE 5000
#define N_NONID 256
#define N_ROWS 2048
#define N_COLS (NUM_PIDS + CQ_SIZE + N_NONID)   // 10788
#define OIM_SCALAR 30.0f
#define KITERS (NUM_FEATURES / 32)              // 8

// Round-4 structure: wave-autonomous 64x64 output tiles. NO LDS, NO
// __syncthreads. Each lane loads its MFMA A/B fragments directly from global
// (2x float4 per frag) and converts fp32->bf16 in VALU. Rationale: r2/r3
// counters showed latency-bound (all pipes <10%, occ 25%); the barriered
// LDS pipeline caps in-flight bytes at ~2 KB/CU vs ~9 KB needed. A fully
// unrolled barrier-free K-loop lets the compiler keep 1-2 whole iterations
// of loads in flight per wave with fine-grained vmcnt. Redundant cross-wave
// reads (A,B = 13 MB total) are absorbed by L1/L2/L3.

typedef __bf16 bf16_t;
typedef __bf16 bf16x8 __attribute__((ext_vector_type(8)));   // MFMA A/B frag
typedef float f32x4 __attribute__((ext_vector_type(4)));     // MFMA C/D frag

#define NT_WAVES ((N_COLS + 63) / 64)           // 169 n wave-tiles
#define NBLK ((NT_WAVES + 3) / 4)               // 43 blocks of 4 waves along n
#define MBLK (N_ROWS / 64)                      // 32

__global__ __launch_bounds__(256, 2)
void oim_gemm_kernel(const float* __restrict__ A,      // [2048][256]
                     const float* __restrict__ lut,    // [5532][256]
                     const float* __restrict__ cq,     // [5000][256]
                     const float* __restrict__ nonid,  // [256][256]
                     float* __restrict__ out) {        // [2048][10788]
    const int tid  = threadIdx.x;
    const int w    = tid >> 6;                  // wave 0..3, adjacent in n
    const int lane = tid & 63;

    const int nt = blockIdx.x * 4 + w;          // n wave-tile index
    if (nt >= NT_WAVES) return;                 // wave-uniform exit (no barriers)
    const int m0 = blockIdx.y * 64;
    const int n0 = nt * 64;

    // MFMA 16x16x32 A/B fragment coords: m(or n)=lane&15, k=(lane>>4)*8 + j
    const int fr = lane & 15;
    const int fk = (lane >> 4) * 8;

    // Per-lane row base pointers (computed once; advance by 32 floats per iter)
    const float* arow[4];
    const float* brow[4];
    #pragma unroll
    for (int t = 0; t < 4; ++t) {
        arow[t] = A + (size_t)(m0 + t * 16 + fr) * NUM_FEATURES + fk;
        int r = n0 + t * 16 + fr;
        r = r < N_COLS ? r : (N_COLS - 1);      // clamp tail (stores guarded)
        const float* src;
        if (r < NUM_PIDS)                 src = lut   + (size_t)r * NUM_FEATURES;
        else if (r < NUM_PIDS + CQ_SIZE)  src = cq    + (size_t)(r - NUM_PIDS) * NUM_FEATURES;
        else                              src = nonid + (size_t)(r - NUM_PIDS - CQ_SIZE) * NUM_FEATURES;
        brow[t] = src + fk;
    }

    f32x4 acc[4][4] = {};

    // Fully unrolled, barrier-free K-loop: 16 independent float4-pair loads
    // per iteration; compiler software-pipelines across iterations with
    // per-wave vmcnt(N) (no barrier to force a vmcnt(0) drain).
    #pragma unroll
    for (int kk = 0; kk < KITERS; ++kk) {
        bf16x8 bfr[4], af[4];
        #pragma unroll
        for (int t = 0; t < 4; ++t) {
            float4 b0 = *(const float4*)(brow[t]);
            float4 b1 = *(const float4*)(brow[t] + 4);
            brow[t] += 32;
            bfr[t] = bf16x8{(bf16_t)b0.x, (bf16_t)b0.y, (bf16_t)b0.z, (bf16_t)b0.w,
                            (bf16_t)b1.x, (bf16_t)b1.y, (bf16_t)b1.z, (bf16_t)b1.w};
        }
        #pragma unroll
        for (int t = 0; t < 4; ++t) {
            float4 a0 = *(const float4*)(arow[t]);
            float4 a1 = *(const float4*)(arow[t] + 4);
            arow[t] += 32;
            af[t] = bf16x8{(bf16_t)a0.x, (bf16_t)a0.y, (bf16_t)a0.z, (bf16_t)a0.w,
                           (bf16_t)a1.x, (bf16_t)a1.y, (bf16_t)a1.z, (bf16_t)a1.w};
        }
        #pragma unroll
        for (int tm = 0; tm < 4; ++tm)
            #pragma unroll
            for (int tn = 0; tn < 4; ++tn)
                acc[tm][tn] = __builtin_amdgcn_mfma_f32_16x16x32_bf16(
                    af[tm], bfr[tn], acc[tm][tn], 0, 0, 0);
    }

    // Epilogue. C/D layout (verified m89/m91): col=lane&15, row=(lane>>4)*4+i.
    // Nontemporal: C is write-once/never-read — keep it from evicting A/B in L2.
    #pragma unroll
    for (int tm = 0; tm < 4; ++tm) {
        const int row_base = m0 + tm * 16 + (lane >> 4) * 4;
        #pragma unroll
        for (int tn = 0; tn < 4; ++tn) {
            const int col = n0 + tn * 16 + fr;
            if (col < N_COLS) {
                #pragma unroll
                for (int i = 0; i < 4; ++i) {
                    __builtin_nontemporal_store(
                        acc[tm][tn][i] * OIM_SCALAR,
                        &out[(size_t)(row_base + i) * N_COLS + col]);
                }
            }
        }
    }
}

extern "C" void kernel_launch(void* const* d_in, const int* in_sizes, int n_in,
                              void* d_out, int out_size, void* d_ws, size_t ws_size,
                              hipStream_t stream) {
    // setup_inputs() order:
    // 0: inputs [2048,256], 1: non_id_feat [256,256], 2: lut [5532,256],
    // 3: cq [5000,256], 4: first_pos_sample, 5: second_pos_sample,
    // 6: targets (int), 7: belong_to_first_half, 8: header
    const float* inputs = (const float*)d_in[0];
    const float* nonid  = (const float*)d_in[1];
    const float* lut    = (const float*)d_in[2];
    const float* cq     = (const float*)d_in[3];
    float* out = (float*)d_out;

    oim_gemm_kernel<<<dim3(NBLK, MBLK), 256, 0, stream>>>(inputs, lut, cq, nonid, out);
}

// Round 5
// 143.711 us; speedup vs baseline: 1.7057x; 1.7057x over previous
//
#include <hip/hip_runtime.h>
#include <hip/hip_bf16.h>
#include <stdint.h>
#include <stddef.h>

// Problem constants (from reference). Harness dtype: fp32 in / fp32 out
// (verified round 2: WRITE_SIZE ~90 MB = 2048*10788*4B).
#define NUM_FEATURES 256
#define NUM_PIDS 5532
#define CQ_SIZE 5000
#define N_NONID 256
#define N_ROWS 2048
#define N_COLS (NUM_PIDS + CQ_SIZE + N_NONID)   // 10788
#define OIM_SCALAR 30.0f

// Tile config: 128x128 tile, BK=32, 4 waves (2x2) each computing 64x64.
// r3 baseline (gemm ~45us). r4's barrier-free direct-global variant regressed
// 3.2x (gather loads + nontemporal write amplification) -- reverted.
#define BM 128
#define BN 128
#define BK 32
#define KITERS (NUM_FEATURES / BK)   // 8

// XCD swizzle: 85 n-tiles padded to 88 = 8 XCDs * 11 tiles. Grid 1408 = 8*176;
// id%8 -> XCD (round-robin dispatch heuristic); each XCD works one contiguous
// 11-tile n-slab: B-slab 1.4 MB + full A 2 MB = 3.4 MB < 4 MB per-XCD L2.
#define NT_PER_XCD 11
#define N_TILES 85
#define M_TILES 16
#define GRID_BLOCKS (8 * NT_PER_XCD * M_TILES)   // 1408 (48 dummy blocks early-exit)

typedef __bf16 bf16_t;
typedef __bf16 bf16x4 __attribute__((ext_vector_type(4)));
typedef __bf16 bf16x8 __attribute__((ext_vector_type(8)));   // MFMA A/B frag
typedef float f32x4 __attribute__((ext_vector_type(4)));     // MFMA C/D frag

__global__ __launch_bounds__(256)
void oim_gemm_kernel(const float* __restrict__ A,      // [2048][256]
                     const float* __restrict__ lut,    // [5532][256]
                     const float* __restrict__ cq,     // [5000][256]
                     const float* __restrict__ nonid,  // [256][256]
                     float* __restrict__ out) {        // [2048][10788]
    // Double-buffered LDS: 2 * (8 KB + 8 KB) = 32 KB
    __shared__ __align__(16) bf16_t As[2][BM * BK];
    __shared__ __align__(16) bf16_t Bs[2][BM * BK];

    // --- XCD-slab block swizzle ---
    const int id  = blockIdx.x;
    const int xcd = id & 7;
    const int l   = id >> 3;                  // 0..175
    const int nt  = xcd * NT_PER_XCD + l % NT_PER_XCD;
    const int mt  = l / NT_PER_XCD;           // 0..15
    if (nt >= N_TILES) return;                // dummy block (uniform, pre-barrier)
    const int m0 = mt * BM;
    const int n0 = nt * BN;

    const int tid  = threadIdx.x;
    const int wid  = tid >> 6;
    const int lane = tid & 63;

    // --- staging coords: each thread loads 4x float4 of A and of B per k-tile
    const int srow = tid >> 3;                // 0..31
    const int skk  = (tid & 7) * 4;           // 0,4,..,28

    const float* arow[4];
    const float* brow[4];
    #pragma unroll
    for (int j = 0; j < 4; ++j) {
        const int rm = m0 + srow + j * 32;
        arow[j] = A + (size_t)rm * NUM_FEATURES + skk;
        int r = n0 + srow + j * 32;
        r = r < (N_COLS - 1) ? r : (N_COLS - 1);   // clamp tail (stores guarded)
        const float* src;
        if (r < NUM_PIDS)                 src = lut   + (size_t)r * NUM_FEATURES;
        else if (r < NUM_PIDS + CQ_SIZE)  src = cq    + (size_t)(r - NUM_PIDS) * NUM_FEATURES;
        else                              src = nonid + (size_t)(r - NUM_PIDS - CQ_SIZE) * NUM_FEATURES;
        brow[j] = src + skk;
    }

    // --- MFMA fragment coords (verified m89/m91) ---
    const int wave_m = (wid >> 1) * 64;
    const int wave_n = (wid & 1) * 64;
    const int fr = lane & 15;                 // A/B frag: m (or n) = lane&15
    const int fk = (lane >> 4) * 8;           // k = (lane>>4)*8 + j

    f32x4 acc[4][4] = {};

    // --- prologue: prefetch k-tile 0 into registers ---
    float4 areg[4], breg[4];
    #pragma unroll
    for (int j = 0; j < 4; ++j) {
        areg[j] = *(const float4*)arow[j];
        breg[j] = *(const float4*)brow[j];
        arow[j] += BK;
        brow[j] += BK;
    }

    // --- single-barrier double-buffered K-loop (fully unrolled) ---
    // Order per iter: cvt+write LDS(kt) -> ISSUE next global loads (regs only,
    // no LDS hazard) -> barrier -> ds_read frags + MFMA. The in-flight loads'
    // latency window spans the barrier wait + ds_read + 16 MFMAs of iter kt,
    // and they are consumed at iter kt+1's LDS write (before its barrier), so
    // no barrier vmcnt(0) drain ever waits on a prefetch (m97 stall avoided).
    #pragma unroll
    for (int kt = 0; kt < KITERS; ++kt) {
        bf16_t* const as = As[kt & 1];
        bf16_t* const bs = Bs[kt & 1];
        #pragma unroll
        for (int j = 0; j < 4; ++j) {
            const int ldix = (srow + j * 32) * BK + skk;
            bf16x4 ac = { (bf16_t)areg[j].x, (bf16_t)areg[j].y,
                          (bf16_t)areg[j].z, (bf16_t)areg[j].w };
            bf16x4 bc = { (bf16_t)breg[j].x, (bf16_t)breg[j].y,
                          (bf16_t)breg[j].z, (bf16_t)breg[j].w };
            *(bf16x4*)&as[ldix] = ac;
            *(bf16x4*)&bs[ldix] = bc;
        }
        if (kt < KITERS - 1) {                // compile-time (full unroll)
            #pragma unroll
            for (int j = 0; j < 4; ++j) {
                areg[j] = *(const float4*)arow[j];
                breg[j] = *(const float4*)brow[j];
                arow[j] += BK;
                brow[j] += BK;
            }
        }
        __syncthreads();

        bf16x8 af[4], bfr[4];
        #pragma unroll
        for (int t = 0; t < 4; ++t) {
            af[t]  = *(const bf16x8*)&as[(wave_m + t * 16 + fr) * BK + fk];
            bfr[t] = *(const bf16x8*)&bs[(wave_n + t * 16 + fr) * BK + fk];
        }
        #pragma unroll
        for (int tm = 0; tm < 4; ++tm)
            #pragma unroll
            for (int tn = 0; tn < 4; ++tn)
                acc[tm][tn] = __builtin_amdgcn_mfma_f32_16x16x32_bf16(
                    af[tm], bfr[tn], acc[tm][tn], 0, 0, 0);
        // no second barrier: double-buffer parity + next iteration's barrier
        // order writes of tile kt+2 after all reads of tile kt.
    }

    // --- epilogue: scale by 30, plain fp32 stores (L2 merges 64B segments;
    // WRITE_SIZE verified exact 90 MB in r2; nontemporal amplified to 150 MB
    // in r4 -- do NOT use nontemporal here) ---
    #pragma unroll
    for (int tm = 0; tm < 4; ++tm) {
        const int row_base = m0 + wave_m + tm * 16 + (lane >> 4) * 4;
        #pragma unroll
        for (int tn = 0; tn < 4; ++tn) {
            const int col = n0 + wave_n + tn * 16 + (lane & 15);
            if (col < N_COLS) {
                #pragma unroll
                for (int i = 0; i < 4; ++i) {
                    out[(size_t)(row_base + i) * N_COLS + col] =
                        acc[tm][tn][i] * OIM_SCALAR;
                }
            }
        }
    }
}

extern "C" void kernel_launch(void* const* d_in, const int* in_sizes, int n_in,
                              void* d_out, int out_size, void* d_ws, size_t ws_size,
                              hipStream_t stream) {
    // setup_inputs() order:
    // 0: inputs [2048,256], 1: non_id_feat [256,256], 2: lut [5532,256],
    // 3: cq [5000,256], 4: first_pos_sample, 5: second_pos_sample,
    // 6: targets (int), 7: belong_to_first_half, 8: header
    const float* inputs = (const float*)d_in[0];
    const float* nonid  = (const float*)d_in[1];
    const float* lut    = (const float*)d_in[2];
    const float* cq     = (const float*)d_in[3];
    float* out = (float*)d_out;

    oim_gemm_kernel<<<dim3(GRID_BLOCKS), 256, 0, stream>>>(inputs, lut, cq, nonid, out);
}